// Round 1
// baseline (3984.949 us; speedup 1.0000x reference)
//
#include <hip/hip_runtime.h>

#define TBM 128
#define TBN 64
#define TBK 16

// C[m][n] = scale * sum_k A[m][k] * (BT ? B[n][k] : B[k][n])  (+ bias[n])
// Batched over blockIdx.z via element strides.
template<bool BT, bool BIAS>
__global__ __launch_bounds__(256)
void gemm_f32(const float* __restrict__ A, int lda, long long strideA,
              const float* __restrict__ B, int ldb, long long strideB,
              float* __restrict__ C, int ldc, long long strideC,
              const float* __restrict__ bias, float scale, int K)
{
    __shared__ float As[TBK][TBM + 4];   // stride 132 floats: conflict-free col reads
    __shared__ float Bs[TBK][TBN + 4];   // stride 68

    const int tid = threadIdx.x;
    const long long z = blockIdx.z;
    const float* Ab = A + z * strideA;
    const float* Bb = B + z * strideB;
    float*       Cb = C + z * strideC;

    const int bm = blockIdx.y * TBM;
    const int bn = blockIdx.x * TBN;

    const int ty = tid >> 4;        // 0..15 -> 8-row group
    const int tx = tid & 15;        // 0..15 -> 4-col group

    const int ar = tid >> 2;        // 0..63
    const int ac = (tid & 3) * 4;   // 0,4,8,12

    float acc[8][4];
    #pragma unroll
    for (int i = 0; i < 8; ++i)
        #pragma unroll
        for (int j = 0; j < 4; ++j) acc[i][j] = 0.f;

    for (int k0 = 0; k0 < K; k0 += TBK) {
        // issue global loads before the barrier (overlap with prior compute)
        const float4 a0 = *(const float4*)&Ab[(size_t)(bm + ar) * lda + k0 + ac];
        const float4 a1 = *(const float4*)&Ab[(size_t)(bm + ar + 64) * lda + k0 + ac];
        float4 b0;
        int bk = 0, bn4 = 0;
        if (BT) {
            b0 = *(const float4*)&Bb[(size_t)(bn + ar) * ldb + k0 + ac];
        } else {
            bk = tid >> 4; bn4 = (tid & 15) * 4;
            b0 = *(const float4*)&Bb[(size_t)(k0 + bk) * ldb + bn + bn4];
        }
        __syncthreads();   // protect previous iteration's LDS reads
        As[ac + 0][ar] = a0.x; As[ac + 1][ar] = a0.y;
        As[ac + 2][ar] = a0.z; As[ac + 3][ar] = a0.w;
        As[ac + 0][ar + 64] = a1.x; As[ac + 1][ar + 64] = a1.y;
        As[ac + 2][ar + 64] = a1.z; As[ac + 3][ar + 64] = a1.w;
        if (BT) {
            Bs[ac + 0][ar] = b0.x; Bs[ac + 1][ar] = b0.y;
            Bs[ac + 2][ar] = b0.z; Bs[ac + 3][ar] = b0.w;
        } else {
            *(float4*)&Bs[bk][bn4] = b0;
        }
        __syncthreads();
        #pragma unroll
        for (int k = 0; k < TBK; ++k) {
            const float4 A0 = *(const float4*)&As[k][ty * 8];
            const float4 A1 = *(const float4*)&As[k][ty * 8 + 4];
            const float4 B0 = *(const float4*)&Bs[k][tx * 4];
            const float a[8] = {A0.x, A0.y, A0.z, A0.w, A1.x, A1.y, A1.z, A1.w};
            const float b[4] = {B0.x, B0.y, B0.z, B0.w};
            #pragma unroll
            for (int i = 0; i < 8; ++i)
                #pragma unroll
                for (int j = 0; j < 4; ++j)
                    acc[i][j] = fmaf(a[i], b[j], acc[i][j]);
        }
    }

    #pragma unroll
    for (int i = 0; i < 8; ++i) {
        float4 v;
        v.x = acc[i][0] * scale; v.y = acc[i][1] * scale;
        v.z = acc[i][2] * scale; v.w = acc[i][3] * scale;
        if (BIAS) {
            const float* bp = &bias[bn + tx * 4];
            v.x += bp[0]; v.y += bp[1]; v.z += bp[2]; v.w += bp[3];
        }
        *(float4*)&Cb[(size_t)(bm + ty * 8 + i) * ldc + bn + tx * 4] = v;
    }
}

__device__ inline float wred_max(float v) {
    #pragma unroll
    for (int off = 32; off > 0; off >>= 1) v = fmaxf(v, __shfl_xor(v, off));
    return v;
}
__device__ inline float wred_sum(float v) {
    #pragma unroll
    for (int off = 32; off > 0; off >>= 1) v += __shfl_xor(v, off);
    return v;
}

// one block (256 threads) per row of 2048 floats; in-place softmax
__global__ __launch_bounds__(256)
void softmax_rows(float* __restrict__ Smat) {
    float* row = Smat + (size_t)blockIdx.x * 2048;
    const int tid = threadIdx.x;
    __shared__ float red[8];
    float v[8];
    float m = -3.4e38f;
    #pragma unroll
    for (int i = 0; i < 8; ++i) { v[i] = row[i * 256 + tid]; m = fmaxf(m, v[i]); }
    m = wred_max(m);
    if ((tid & 63) == 0) red[tid >> 6] = m;
    __syncthreads();
    m = fmaxf(fmaxf(red[0], red[1]), fmaxf(red[2], red[3]));
    float s = 0.f;
    #pragma unroll
    for (int i = 0; i < 8; ++i) { v[i] = __expf(v[i] - m); s += v[i]; }
    s = wred_sum(s);
    if ((tid & 63) == 0) red[4 + (tid >> 6)] = s;
    __syncthreads();
    s = red[4] + red[5] + red[6] + red[7];
    const float inv = 1.f / s;
    #pragma unroll
    for (int i = 0; i < 8; ++i) row[i * 256 + tid] = v[i] * inv;
}

extern "C" void kernel_launch(void* const* d_in, const int* in_sizes, int n_in,
                              void* d_out, int out_size, void* d_ws, size_t ws_size,
                              hipStream_t stream) {
    const float* x    = (const float*)d_in[0];   // [8,2048,1024]
    const float* W    = (const float*)d_in[1];   // [1024,3072]
    const float* bias = (const float*)d_in[2];   // [3072]
    float* out = (float*)d_out;                  // [8,2048,1024]

    const int B = 8, S = 2048, E = 1024;
    const int M  = B * S;     // 16384
    const int N3 = 3 * E;     // 3072
    const float sc = 1.0f / 32.0f;   // 1/sqrt(1024)

    float* qkv = (float*)d_ws;                       // [M][3E] fp32, 192 MiB
    const size_t qkv_elems = (size_t)M * N3;
    float* scores = qkv + qkv_elems;

    const size_t need_full = (qkv_elems + (size_t)B * S * S) * sizeof(float);
    const bool full = ws_size >= need_full;

    const dim3 blk(256);

    // 1) qkv = x @ W + b   (B is [K][N] -> BT=false)
    gemm_f32<false, true><<<dim3(N3 / TBN, M / TBM, 1), blk, 0, stream>>>(
        x, E, 0, W, N3, 0, qkv, N3, 0, bias, 1.0f, E);

    if (full) {
        // 2) scores = Q @ K^T * sc, batched over z
        gemm_f32<true, false><<<dim3(S / TBN, S / TBM, B), blk, 0, stream>>>(
            qkv + 0, N3, (long long)S * N3,
            qkv + E, N3, (long long)S * N3,
            scores, S, (long long)S * S, nullptr, sc, E);
        // 3) softmax rows
        softmax_rows<<<B * S, blk, 0, stream>>>(scores);
        // 4) out = P @ V
        gemm_f32<false, false><<<dim3(E / TBN, S / TBM, B), blk, 0, stream>>>(
            scores, S, (long long)S * S,
            qkv + 2 * E, N3, (long long)S * N3,
            out, E, (long long)S * E, nullptr, 1.0f, S);
    } else {
        for (int b = 0; b < B; ++b) {
            const float* Qb = qkv + (size_t)b * S * N3;
            const float* Kb = Qb + E;
            const float* Vb = Qb + 2 * E;
            float* outb = out + (size_t)b * S * E;
            gemm_f32<true, false><<<dim3(S / TBN, S / TBM, 1), blk, 0, stream>>>(
                Qb, N3, 0, Kb, N3, 0, scores, S, 0, nullptr, sc, E);
            softmax_rows<<<S, blk, 0, stream>>>(scores);
            gemm_f32<false, false><<<dim3(E / TBN, S / TBM, 1), blk, 0, stream>>>(
                scores, S, 0, Vb, N3, 0, outb, E, 0, nullptr, 1.0f, S);
        }
    }
}

// Round 2
// 427.478 us; speedup vs baseline: 9.3220x; 9.3220x over previous
//
#include <hip/hip_runtime.h>

typedef unsigned short u16;
typedef unsigned int u32;
typedef __attribute__((ext_vector_type(8))) short short8;
typedef __attribute__((ext_vector_type(4))) short short4v;
typedef __attribute__((ext_vector_type(4))) float f32x4;

__device__ __forceinline__ u16 f2bf(float f) {
    u32 u = __float_as_uint(f);
    u32 r = (u + 0x7fffu + ((u >> 16) & 1u)) >> 16;   // RNE
    return (u16)r;
}
__device__ __forceinline__ float bf2f(u16 h) {
    return __uint_as_float(((u32)h) << 16);
}

__device__ __forceinline__ void gload_lds16(const void* g, void* l) {
    __builtin_amdgcn_global_load_lds((const __attribute__((address_space(1))) void*)g,
                                     (__attribute__((address_space(3))) void*)l, 16, 0, 0);
}

// ---------------------------------------------------------------------------
// bf16 MFMA GEMM, m97 structure: 128x128 tile, BK=32, 4 waves, 2-barrier loop.
// A [M][K] row-major (lda), B stored TRANSPOSED [N][K] row-major (ldb).
// C[m][n] = scale * sum_k A[m][k]*B[n][k]  (+bias[n] if EPI==0)
// EPI: 0 = bf16 out + bias, 1 = bf16 out (scaled), 2 = f32 out (scaled)
// ---------------------------------------------------------------------------
#define BM 128
#define BN 128
#define BKK 32

template<int EPI>
__global__ __launch_bounds__(256)
void gemm_bf16(const u16* __restrict__ A, int lda, long long sA,
               const u16* __restrict__ B, int ldb, long long sB,
               void* __restrict__ Cv, int ldc, long long sC,
               const float* __restrict__ bias, float scale, int K)
{
    __shared__ __align__(16) u16 As[BM][BKK];
    __shared__ __align__(16) u16 Bs[BN][BKK];

    const int tid  = threadIdx.x;
    const int wid  = tid >> 6;
    const int lane = tid & 63;
    const int z    = blockIdx.z;

    const u16* Ab = A + (long long)z * sA;
    const u16* Bb = B + (long long)z * sB;

    const int bm = blockIdx.y * BM;
    const int bn = blockIdx.x * BN;
    const int wr = wid >> 1, wc = wid & 1;

    // staging: lane l covers row (l>>2), 8 elems at (l&3)*8 -> LDS byte l*16
    const int srow = lane >> 2;
    const int scol = (lane & 3) * 8;

    f32x4 acc[4][4];
    #pragma unroll
    for (int m = 0; m < 4; ++m)
        #pragma unroll
        for (int n = 0; n < 4; ++n)
            #pragma unroll
            for (int r = 0; r < 4; ++r) acc[m][n][r] = 0.f;

    const int frow = lane & 15;
    const int fk   = (lane >> 4) * 8;

    for (int k0 = 0; k0 < K; k0 += BKK) {
        __syncthreads();   // all waves done reading previous tile
        #pragma unroll
        for (int i = 0; i < 2; ++i) {
            const int r = wid * 32 + i * 16;     // wave-uniform
            gload_lds16(Ab + (size_t)(bm + r + srow) * lda + (k0 + scol), &As[r][0]);
            gload_lds16(Bb + (size_t)(bn + r + srow) * ldb + (k0 + scol), &Bs[r][0]);
        }
        __syncthreads();   // drains vmcnt -> LDS populated

        short8 af[4], bfr[4];
        #pragma unroll
        for (int m = 0; m < 4; ++m)
            af[m] = *(const short8*)&As[wr * 64 + m * 16 + frow][fk];
        #pragma unroll
        for (int n = 0; n < 4; ++n)
            bfr[n] = *(const short8*)&Bs[wc * 64 + n * 16 + frow][fk];
        #pragma unroll
        for (int m = 0; m < 4; ++m)
            #pragma unroll
            for (int n = 0; n < 4; ++n)
                acc[m][n] = __builtin_amdgcn_mfma_f32_16x16x32_bf16(af[m], bfr[n], acc[m][n], 0, 0, 0);
    }

    // C/D layout (m89-verified): col = lane&15, row = 4*(lane>>4) + reg
    const int c0 = (lane >> 4) * 4;
    const int cc = lane & 15;

    if (EPI == 2) {
        float* C = (float*)Cv + (long long)z * sC;
        #pragma unroll
        for (int m = 0; m < 4; ++m) {
            const int row = bm + wr * 64 + m * 16 + c0;
            #pragma unroll
            for (int n = 0; n < 4; ++n) {
                const int col = bn + wc * 64 + n * 16 + cc;
                #pragma unroll
                for (int r = 0; r < 4; ++r)
                    C[(size_t)(row + r) * ldc + col] = acc[m][n][r] * scale;
            }
        }
    } else {
        u16* C = (u16*)Cv + (long long)z * sC;
        #pragma unroll
        for (int n = 0; n < 4; ++n) {
            const int col = bn + wc * 64 + n * 16 + cc;
            const float badd = (EPI == 0) ? bias[col] : 0.f;
            #pragma unroll
            for (int m = 0; m < 4; ++m) {
                const int row = bm + wr * 64 + m * 16 + c0;
                #pragma unroll
                for (int r = 0; r < 4; ++r)
                    C[(size_t)(row + r) * ldc + col] = f2bf(acc[m][n][r] * scale + badd);
            }
        }
    }
}

// ---------------------------------------------------------------------------
__global__ __launch_bounds__(256)
void cvt_f32_bf16(const float* __restrict__ in, u16* __restrict__ out, int n8)
{
    const int i = blockIdx.x * 256 + threadIdx.x;
    if (i >= n8) return;
    const float4* p = (const float4*)in;
    const float4 a = p[2 * i], b = p[2 * i + 1];
    short8 o;
    o[0] = (short)f2bf(a.x); o[1] = (short)f2bf(a.y);
    o[2] = (short)f2bf(a.z); o[3] = (short)f2bf(a.w);
    o[4] = (short)f2bf(b.x); o[5] = (short)f2bf(b.y);
    o[6] = (short)f2bf(b.z); o[7] = (short)f2bf(b.w);
    ((short8*)out)[i] = o;
}

// W [1024][3072] f32 -> Wt [3072][1024] bf16 (transpose + convert)
__global__ __launch_bounds__(256)
void cvt_w_t(const float* __restrict__ W, u16* __restrict__ Wt)
{
    __shared__ u16 T[32][33];
    const int tid = threadIdx.x;
    const int tr = tid >> 3;
    const int tc = (tid & 7) * 4;
    const int c0 = blockIdx.x * 32;
    const int r0 = blockIdx.y * 32;
    const float4 v = *(const float4*)&W[(size_t)(r0 + tr) * 3072 + c0 + tc];
    T[tr][tc + 0] = f2bf(v.x); T[tr][tc + 1] = f2bf(v.y);
    T[tr][tc + 2] = f2bf(v.z); T[tr][tc + 3] = f2bf(v.w);
    __syncthreads();
    short4v o;
    o[0] = (short)T[tc + 0][tr]; o[1] = (short)T[tc + 1][tr];
    o[2] = (short)T[tc + 2][tr]; o[3] = (short)T[tc + 3][tr];
    *(short4v*)&Wt[(size_t)(c0 + tr) * 1024 + r0 + tc] = o;
}

// qkv bf16 [B*2048][3072], V at cols 2048.. -> Vt [B][1024][2048] bf16
__global__ __launch_bounds__(256)
void trans_v(const u16* __restrict__ qkv, u16* __restrict__ Vt)
{
    __shared__ u16 T[32][33];
    const int tid = threadIdx.x;
    const int tr = tid >> 3;
    const int tc = (tid & 7) * 4;
    const int e0 = blockIdx.x * 32;
    const int s0 = blockIdx.y * 32;
    const int b  = blockIdx.z;
    const short4v v = *(const short4v*)&qkv[(size_t)(b * 2048 + s0 + tr) * 3072 + 2048 + e0 + tc];
    T[tr][tc + 0] = (u16)v[0]; T[tr][tc + 1] = (u16)v[1];
    T[tr][tc + 2] = (u16)v[2]; T[tr][tc + 3] = (u16)v[3];
    __syncthreads();
    short4v o;
    o[0] = (short)T[tc + 0][tr]; o[1] = (short)T[tc + 1][tr];
    o[2] = (short)T[tc + 2][tr]; o[3] = (short)T[tc + 3][tr];
    *(short4v*)&Vt[(size_t)b * 1024 * 2048 + (size_t)(e0 + tr) * 2048 + s0 + tc] = o;
}

// in-place row softmax over 2048 bf16
__global__ __launch_bounds__(256)
void softmax_bf16(u16* __restrict__ S)
{
    u16* row = S + (size_t)blockIdx.x * 2048;
    const int tid  = threadIdx.x;
    const int wid  = tid >> 6;
    const int lane = tid & 63;
    __shared__ float red[4];

    const short8 v8 = *(const short8*)&row[tid * 8];
    float v[8];
    float m = -3.4e38f;
    #pragma unroll
    for (int j = 0; j < 8; ++j) { v[j] = bf2f((u16)v8[j]); m = fmaxf(m, v[j]); }
    #pragma unroll
    for (int off = 32; off; off >>= 1) m = fmaxf(m, __shfl_xor(m, off));
    if (lane == 0) red[wid] = m;
    __syncthreads();
    m = fmaxf(fmaxf(red[0], red[1]), fmaxf(red[2], red[3]));
    float s = 0.f;
    #pragma unroll
    for (int j = 0; j < 8; ++j) { v[j] = __expf(v[j] - m); s += v[j]; }
    #pragma unroll
    for (int off = 32; off; off >>= 1) s += __shfl_xor(s, off);
    __syncthreads();
    if (lane == 0) red[wid] = s;
    __syncthreads();
    s = red[0] + red[1] + red[2] + red[3];
    const float inv = 1.f / s;
    short8 o;
    #pragma unroll
    for (int j = 0; j < 8; ++j) o[j] = (short)f2bf(v[j] * inv);
    *(short8*)&row[tid * 8] = o;
}

// ---------------------------------------------------------------------------
extern "C" void kernel_launch(void* const* d_in, const int* in_sizes, int n_in,
                              void* d_out, int out_size, void* d_ws, size_t ws_size,
                              hipStream_t stream) {
    const float* x    = (const float*)d_in[0];   // [8,2048,1024]
    const float* W    = (const float*)d_in[1];   // [1024,3072]
    const float* bias = (const float*)d_in[2];   // [3072]
    float* out = (float*)d_out;                  // [8,2048,1024] f32

    const int B = 8, S = 2048, E = 1024, N3 = 3072;
    const int M = B * S;                         // 16384

    char* ws = (char*)d_ws;
    u16* xb   = (u16*)ws;                          // 32 MiB  [M][E] bf16
    u16* Wtb  = (u16*)(ws + 33554432);             //  6 MiB  [3072][1024] bf16
    u16* qkvb = (u16*)(ws + 39845888);             // 96 MiB  [M][3072] bf16
    u16* Vtb  = (u16*)(ws + 140509184);            // 32 MiB  [B][1024][2048] bf16
    u16* Sb   = (u16*)(ws + 174063616);            // 64 MiB full / 8 MiB per-batch

    const size_t need_full = 174063616ull + (size_t)B * S * S * 2;
    const bool full = ws_size >= need_full;
    const float sc = 1.0f / 32.0f;

    cvt_f32_bf16<<<dim3((M * E) / 8 / 256), 256, 0, stream>>>(x, xb, (M * E) / 8);
    cvt_w_t<<<dim3(96, 32), 256, 0, stream>>>(W, Wtb);

    // qkv = x @ W + b  (bf16 out)
    gemm_bf16<0><<<dim3(N3 / 128, M / 128, 1), 256, 0, stream>>>(
        xb, E, 0, Wtb, E, 0, qkvb, N3, 0, bias, 1.0f, E);

    trans_v<<<dim3(32, 64, 8), 256, 0, stream>>>(qkvb, Vtb);

    if (full) {
        gemm_bf16<1><<<dim3(S / 128, S / 128, 8), 256, 0, stream>>>(
            qkvb, N3, (long long)S * N3, qkvb + E, N3, (long long)S * N3,
            Sb, S, (long long)S * S, nullptr, sc, E);
        softmax_bf16<<<dim3(B * S), 256, 0, stream>>>(Sb);
        gemm_bf16<2><<<dim3(E / 128, S / 128, 8), 256, 0, stream>>>(
            Sb, S, (long long)S * S, Vtb, S, (long long)E * S,
            out, E, (long long)S * E, nullptr, 1.0f, S);
    } else {
        for (int b = 0; b < B; ++b) {
            const u16* Qb = qkvb + (size_t)b * S * N3;
            gemm_bf16<1><<<dim3(S / 128, S / 128, 1), 256, 0, stream>>>(
                Qb, N3, 0, Qb + E, N3, 0, Sb, S, 0, nullptr, sc, E);
            softmax_bf16<<<dim3(S), 256, 0, stream>>>(Sb);
            gemm_bf16<2><<<dim3(E / 128, S / 128, 1), 256, 0, stream>>>(
                Sb, S, 0, Vtb + (size_t)b * E * S, S, 0,
                out + (size_t)b * S * E, E, 0, nullptr, 1.0f, S);
        }
    }
}

// Round 3
// 313.964 us; speedup vs baseline: 12.6924x; 1.3616x over previous
//
#include <hip/hip_runtime.h>

typedef unsigned short u16;
typedef unsigned int u32;
typedef __attribute__((ext_vector_type(8))) short short8;
typedef __attribute__((ext_vector_type(4))) short short4v;
typedef __attribute__((ext_vector_type(4))) float f32x4;

__device__ __forceinline__ u16 f2bf(float f) {
    u32 u = __float_as_uint(f);
    u32 r = (u + 0x7fffu + ((u >> 16) & 1u)) >> 16;   // RNE
    return (u16)r;
}
__device__ __forceinline__ float bf2f(u16 h) {
    return __uint_as_float(((u32)h) << 16);
}

__device__ __forceinline__ void gload_lds16(const void* g, void* l) {
    __builtin_amdgcn_global_load_lds((const __attribute__((address_space(1))) void*)g,
                                     (__attribute__((address_space(3))) void*)l, 16, 0, 0);
}

#define BARRIER() do { __builtin_amdgcn_sched_barrier(0); __builtin_amdgcn_s_barrier(); __builtin_amdgcn_sched_barrier(0); } while (0)
#define VMCNT(N)  asm volatile("s_waitcnt vmcnt(" #N ")" ::: "memory")

// ---------------------------------------------------------------------------
// 256x256 8-phase bf16 MFMA GEMM (T2 swizzle + T3/T4 counted vmcnt + T5 setprio)
// A [M][K] row-major; B stored TRANSPOSED [N][K] row-major.
// C = scale * A @ B^T (+ bias[n] if EPI==0)
// EPI: 0 = bf16 out + bias, 1 = bf16 out scaled, 2 = f32 out scaled
// LDS (dynamic, 128 KiB): buf0A@0  buf0B@32768  buf1A@65536  buf1B@98304
// Each operand region: [256 rows][64 cols bf16] = 128 B/row, slot-swizzled:
//   LDS[row][slot s] = G[row][slot s ^ (row&7)]   (slot = 16B unit)
// ---------------------------------------------------------------------------

// stage 64 rows (one global_load_lds round = 512 thr x 16 B = 8 KiB)
__device__ __forceinline__ void stage_half(const u16* __restrict__ gtile, int ldg, int kcol0,
                                           char* lds, int regionOff, int r0,
                                           int wid, int lane)
{
    const int cc = kcol0 + (((lane & 7) ^ (lane >> 3)) << 3);  // inverse-swizzled src col (elems)
    #pragma unroll
    for (int j = 0; j < 2; ++j) {
        const int rbase = r0 + j * 64 + (wid << 3);            // wave-uniform
        gload_lds16(gtile + (size_t)(rbase + (lane >> 3)) * ldg + cc,
                    lds + regionOff + (size_t)rbase * 128);
    }
}

template<int ROFF, int QH>
__device__ __forceinline__ void ld_a(short8 (&a)[4][2], const char* lds, int arow, const int colk[2]) {
    #pragma unroll
    for (int mf = 0; mf < 4; ++mf)
        #pragma unroll
        for (int kh = 0; kh < 2; ++kh)
            a[mf][kh] = *(const short8*)(lds + ROFF + QH * 16384 + mf * 2048 + arow + colk[kh]);
}
template<int ROFF, int QH>
__device__ __forceinline__ void ld_b(short8 (&b)[2][2], const char* lds, int brow, const int colk[2]) {
    #pragma unroll
    for (int nf = 0; nf < 2; ++nf)
        #pragma unroll
        for (int kh = 0; kh < 2; ++kh)
            b[nf][kh] = *(const short8*)(lds + ROFF + QH * 16384 + nf * 2048 + brow + colk[kh]);
}

template<int QM, int QN>
__device__ __forceinline__ void mfq(f32x4 (&acc)[2][4][2][2], short8 (&a)[4][2], short8 (&b)[2][2]) {
    __builtin_amdgcn_s_setprio(1);
    #pragma unroll
    for (int mf = 0; mf < 4; ++mf)
        #pragma unroll
        for (int nf = 0; nf < 2; ++nf) {
            acc[QM][mf][QN][nf] = __builtin_amdgcn_mfma_f32_16x16x32_bf16(a[mf][0], b[nf][0], acc[QM][mf][QN][nf], 0, 0, 0);
            acc[QM][mf][QN][nf] = __builtin_amdgcn_mfma_f32_16x16x32_bf16(a[mf][1], b[nf][1], acc[QM][mf][QN][nf], 0, 0, 0);
        }
    __builtin_amdgcn_s_setprio(0);
}

template<int EPI>
__global__ __launch_bounds__(512, 2)
void gemm8p(const u16* __restrict__ A, int lda, long long sA,
            const u16* __restrict__ B, int ldb, long long sB,
            void* __restrict__ Cv, int ldc, long long sC,
            const float* __restrict__ bias, float scale, int K)
{
    extern __shared__ char lds[];
    const int tid  = threadIdx.x;
    const int wid  = tid >> 6;
    const int lane = tid & 63;
    const long long z = blockIdx.z;

    const int bm = blockIdx.y * 256;
    const int bn = blockIdx.x * 256;
    const u16* Atile = A + z * sA + (size_t)bm * lda;
    const u16* Btile = B + z * sB + (size_t)bn * ldb;

    const int wm = wid >> 2;   // 0..1
    const int wn = wid & 3;    // 0..3

    const int l15  = lane & 15;
    const int lxor = (lane & 7) << 4;
    const int khi  = (lane >> 4) << 4;
    const int colk[2] = { khi ^ lxor, (64 + khi) ^ lxor };
    const int arow = (wm * 64 + l15) * 128;
    const int brow = (wn * 32 + l15) * 128;

    f32x4 acc[2][4][2][2];
    #pragma unroll
    for (int i = 0; i < 2; ++i)
        #pragma unroll
        for (int m = 0; m < 4; ++m)
            #pragma unroll
            for (int j = 0; j < 2; ++j)
                #pragma unroll
                for (int n = 0; n < 2; ++n)
                    acc[i][m][j][n] = (f32x4){0.f, 0.f, 0.f, 0.f};

    const int NT = K >> 6;     // 64-wide K tiles (even by construction)
    const int NI = NT >> 1;

    // prologue: tile0 all 4 halves, tile1 A-h0/B-h0
    stage_half(Atile, lda, 0,  lds, 0,     0,   wid, lane);
    stage_half(Btile, ldb, 0,  lds, 32768, 0,   wid, lane);
    stage_half(Atile, lda, 0,  lds, 0,     128, wid, lane);
    stage_half(Btile, ldb, 0,  lds, 32768, 128, wid, lane);
    stage_half(Atile, lda, 64, lds, 65536, 0,   wid, lane);
    stage_half(Btile, ldb, 64, lds, 98304, 0,   wid, lane);
    VMCNT(4);                  // tile0's 8 loads retired; tile1's 4 in flight
    BARRIER();

    short8 a[4][2], b[2][2];

    for (int it = 0; it < NI; ++it) {
        const int k1 = (2 * it + 1) << 6;
        const int k2 = (2 * it + 2) << 6;
        const int k3 = (2 * it + 3) << 6;
        const bool lastit = (it == NI - 1);

        // ph1: compute t.Q(0,0); stage (t+1).A-h1 (region free since prev ph7)
        ld_a<0, 0>(a, lds, arow, colk);
        ld_b<32768, 0>(b, lds, brow, colk);
        stage_half(Atile, lda, k1, lds, 65536, 128, wid, lane);
        BARRIER(); mfq<0, 0>(acc, a, b); BARRIER();
        // ph2: t.Q(0,1); stage (t+1).B-h1 (free since prev ph8)
        ld_b<32768, 1>(b, lds, brow, colk);
        stage_half(Btile, ldb, k1, lds, 98304, 128, wid, lane);
        BARRIER(); mfq<0, 1>(acc, a, b); BARRIER();
        // ph3: t.Q(1,0); stage (t+2).A-h0 (A-h0 dead since ph1)
        ld_a<0, 1>(a, lds, arow, colk);
        ld_b<32768, 0>(b, lds, brow, colk);
        if (!lastit) stage_half(Atile, lda, k2, lds, 0, 0, wid, lane);
        BARRIER(); mfq<1, 0>(acc, a, b); BARRIER();
        // ph4: t.Q(1,1); stage (t+2).B-h0 (dead since ph3); gate tile t+1
        ld_b<32768, 1>(b, lds, brow, colk);
        if (!lastit) { stage_half(Btile, ldb, k2, lds, 32768, 0, wid, lane); VMCNT(4); }
        else         { VMCNT(0); }
        BARRIER(); mfq<1, 1>(acc, a, b); BARRIER();
        // ph5: (t+1).Q(0,0); stage (t+2).A-h1 (dead since ph3)
        ld_a<65536, 0>(a, lds, arow, colk);
        ld_b<98304, 0>(b, lds, brow, colk);
        if (!lastit) stage_half(Atile, lda, k2, lds, 0, 128, wid, lane);
        BARRIER(); mfq<0, 0>(acc, a, b); BARRIER();
        // ph6: (t+1).Q(0,1); stage (t+2).B-h1 (dead since ph4)
        ld_b<98304, 1>(b, lds, brow, colk);
        if (!lastit) stage_half(Btile, ldb, k2, lds, 32768, 128, wid, lane);
        BARRIER(); mfq<0, 1>(acc, a, b); BARRIER();
        // ph7: (t+1).Q(1,0); stage (t+3).A-h0 (dead since ph5)
        ld_a<65536, 1>(a, lds, arow, colk);
        ld_b<98304, 0>(b, lds, brow, colk);
        if (!lastit) stage_half(Atile, lda, k3, lds, 65536, 0, wid, lane);
        BARRIER(); mfq<1, 0>(acc, a, b); BARRIER();
        // ph8: (t+1).Q(1,1); stage (t+3).B-h0 (dead since ph7); gate tile t+2
        ld_b<98304, 1>(b, lds, brow, colk);
        if (!lastit) { stage_half(Btile, ldb, k3, lds, 98304, 0, wid, lane); VMCNT(4); }
        BARRIER(); mfq<1, 1>(acc, a, b); BARRIER();
    }

    // epilogue. C/D map (m89): col = lane&15, row = 4*(lane>>4)+reg
    const int r0 = (lane >> 4) * 4;
    const int cc = lane & 15;
    #pragma unroll
    for (int qn = 0; qn < 2; ++qn)
        #pragma unroll
        for (int nf = 0; nf < 2; ++nf) {
            const int col = bn + qn * 128 + wn * 32 + nf * 16 + cc;
            const float badd = (EPI == 0) ? bias[col] : 0.f;
            #pragma unroll
            for (int qm = 0; qm < 2; ++qm)
                #pragma unroll
                for (int mf = 0; mf < 4; ++mf) {
                    const int row = bm + qm * 128 + wm * 64 + mf * 16 + r0;
                    #pragma unroll
                    for (int r = 0; r < 4; ++r) {
                        const float v = acc[qm][mf][qn][nf][r] * scale + badd;
                        if (EPI == 2) ((float*)Cv + z * sC)[(size_t)(row + r) * ldc + col] = v;
                        else          ((u16*)Cv + z * sC)[(size_t)(row + r) * ldc + col] = f2bf(v);
                    }
                }
        }
}

// ---------------------------------------------------------------------------
__global__ __launch_bounds__(256)
void cvt_f32_bf16(const float* __restrict__ in, u16* __restrict__ out, int n8)
{
    const int i = blockIdx.x * 256 + threadIdx.x;
    if (i >= n8) return;
    const float4* p = (const float4*)in;
    const float4 a = p[2 * i], b = p[2 * i + 1];
    short8 o;
    o[0] = (short)f2bf(a.x); o[1] = (short)f2bf(a.y);
    o[2] = (short)f2bf(a.z); o[3] = (short)f2bf(a.w);
    o[4] = (short)f2bf(b.x); o[5] = (short)f2bf(b.y);
    o[6] = (short)f2bf(b.z); o[7] = (short)f2bf(b.w);
    ((short8*)out)[i] = o;
}

// W [1024][3072] f32 -> Wt [3072][1024] bf16
__global__ __launch_bounds__(256)
void cvt_w_t(const float* __restrict__ W, u16* __restrict__ Wt)
{
    __shared__ u16 T[32][33];
    const int tid = threadIdx.x;
    const int tr = tid >> 3;
    const int tc = (tid & 7) * 4;
    const int c0 = blockIdx.x * 32;
    const int r0 = blockIdx.y * 32;
    const float4 v = *(const float4*)&W[(size_t)(r0 + tr) * 3072 + c0 + tc];
    T[tr][tc + 0] = f2bf(v.x); T[tr][tc + 1] = f2bf(v.y);
    T[tr][tc + 2] = f2bf(v.z); T[tr][tc + 3] = f2bf(v.w);
    __syncthreads();
    short4v o;
    o[0] = (short)T[tc + 0][tr]; o[1] = (short)T[tc + 1][tr];
    o[2] = (short)T[tc + 2][tr]; o[3] = (short)T[tc + 3][tr];
    *(short4v*)&Wt[(size_t)(c0 + tr) * 1024 + r0 + tc] = o;
}

// qkv bf16 [B*2048][3072], V at cols 2048.. -> Vt [B][1024][2048]
__global__ __launch_bounds__(256)
void trans_v(const u16* __restrict__ qkv, u16* __restrict__ Vt)
{
    __shared__ u16 T[32][33];
    const int tid = threadIdx.x;
    const int tr = tid >> 3;
    const int tc = (tid & 7) * 4;
    const int e0 = blockIdx.x * 32;
    const int s0 = blockIdx.y * 32;
    const int b  = blockIdx.z;
    const short4v v = *(const short4v*)&qkv[(size_t)(b * 2048 + s0 + tr) * 3072 + 2048 + e0 + tc];
    T[tr][tc + 0] = (u16)v[0]; T[tr][tc + 1] = (u16)v[1];
    T[tr][tc + 2] = (u16)v[2]; T[tr][tc + 3] = (u16)v[3];
    __syncthreads();
    short4v o;
    o[0] = (short)T[tc + 0][tr]; o[1] = (short)T[tc + 1][tr];
    o[2] = (short)T[tc + 2][tr]; o[3] = (short)T[tc + 3][tr];
    *(short4v*)&Vt[(size_t)b * 1024 * 2048 + (size_t)(e0 + tr) * 2048 + s0 + tc] = o;
}

// in-place row softmax over 2048 bf16
__global__ __launch_bounds__(256)
void softmax_bf16(u16* __restrict__ S)
{
    u16* row = S + (size_t)blockIdx.x * 2048;
    const int tid  = threadIdx.x;
    const int wid  = tid >> 6;
    const int lane = tid & 63;
    __shared__ float red[4];

    const short8 v8 = *(const short8*)&row[tid * 8];
    float v[8];
    float m = -3.4e38f;
    #pragma unroll
    for (int j = 0; j < 8; ++j) { v[j] = bf2f((u16)v8[j]); m = fmaxf(m, v[j]); }
    #pragma unroll
    for (int off = 32; off; off >>= 1) m = fmaxf(m, __shfl_xor(m, off));
    if (lane == 0) red[wid] = m;
    __syncthreads();
    m = fmaxf(fmaxf(red[0], red[1]), fmaxf(red[2], red[3]));
    float s = 0.f;
    #pragma unroll
    for (int j = 0; j < 8; ++j) { v[j] = __expf(v[j] - m); s += v[j]; }
    #pragma unroll
    for (int off = 32; off; off >>= 1) s += __shfl_xor(s, off);
    __syncthreads();
    if (lane == 0) red[wid] = s;
    __syncthreads();
    s = red[0] + red[1] + red[2] + red[3];
    const float inv = 1.f / s;
    short8 o;
    #pragma unroll
    for (int j = 0; j < 8; ++j) o[j] = (short)f2bf(v[j] * inv);
    *(short8*)&row[tid * 8] = o;
}

// ---------------------------------------------------------------------------
extern "C" void kernel_launch(void* const* d_in, const int* in_sizes, int n_in,
                              void* d_out, int out_size, void* d_ws, size_t ws_size,
                              hipStream_t stream) {
    const float* x    = (const float*)d_in[0];   // [8,2048,1024]
    const float* W    = (const float*)d_in[1];   // [1024,3072]
    const float* bias = (const float*)d_in[2];   // [3072]
    float* out = (float*)d_out;                  // [8,2048,1024] f32

    const int B = 8, S = 2048, E = 1024, N3 = 3072;
    const int M = B * S;                         // 16384

    char* ws = (char*)d_ws;
    u16* xb   = (u16*)ws;                          // 32 MiB  [M][E]
    u16* Wtb  = (u16*)(ws + 33554432);             //  6 MiB  [3072][1024]
    u16* qkvb = (u16*)(ws + 39845888);             // 96 MiB  [M][3072]
    u16* Vtb  = (u16*)(ws + 140509184);            // 32 MiB  [B][1024][2048]
    u16* Sb   = (u16*)(ws + 174063616);            // 64 MiB full / 8 MiB per-batch

    const size_t need_full = 174063616ull + (size_t)B * S * S * 2;
    const bool full = ws_size >= need_full;
    const float sc = 1.0f / 32.0f;
    const int LDSB = 131072;

    (void)hipFuncSetAttribute(reinterpret_cast<const void*>(&gemm8p<0>),
                              hipFuncAttributeMaxDynamicSharedMemorySize, LDSB);
    (void)hipFuncSetAttribute(reinterpret_cast<const void*>(&gemm8p<1>),
                              hipFuncAttributeMaxDynamicSharedMemorySize, LDSB);
    (void)hipFuncSetAttribute(reinterpret_cast<const void*>(&gemm8p<2>),
                              hipFuncAttributeMaxDynamicSharedMemorySize, LDSB);

    cvt_f32_bf16<<<dim3((M * E) / 8 / 256), 256, 0, stream>>>(x, xb, (M * E) / 8);
    cvt_w_t<<<dim3(96, 32), 256, 0, stream>>>(W, Wtb);

    // qkv = x @ W + b
    gemm8p<0><<<dim3(N3 / 256, M / 256, 1), 512, LDSB, stream>>>(
        xb, E, 0, Wtb, E, 0, qkvb, N3, 0, bias, 1.0f, E);

    trans_v<<<dim3(32, 64, 8), 256, 0, stream>>>(qkvb, Vtb);

    if (full) {
        gemm8p<1><<<dim3(S / 256, S / 256, 8), 512, LDSB, stream>>>(
            qkvb, N3, (long long)S * N3, qkvb + E, N3, (long long)S * N3,
            Sb, S, (long long)S * S, nullptr, sc, E);
        softmax_bf16<<<dim3(B * S), 256, 0, stream>>>(Sb);
        gemm8p<2><<<dim3(E / 256, S / 256, 8), 512, LDSB, stream>>>(
            Sb, S, (long long)S * S, Vtb, S, (long long)E * S,
            out, E, (long long)S * E, nullptr, 1.0f, S);
    } else {
        for (int b = 0; b < B; ++b) {
            const u16* Qb = qkvb + (size_t)b * S * N3;
            gemm8p<1><<<dim3(S / 256, S / 256, 1), 512, LDSB, stream>>>(
                Qb, N3, 0, Qb + E, N3, 0, Sb, S, 0, nullptr, sc, E);
            softmax_bf16<<<dim3(S), 256, 0, stream>>>(Sb);
            gemm8p<2><<<dim3(E / 256, S / 256, 1), 512, LDSB, stream>>>(
                Sb, S, 0, Vtb + (size_t)b * E * S, S, 0,
                out + (size_t)b * S * E, E, 0, nullptr, 1.0f, S);
        }
    }
}

// Round 4
// 292.652 us; speedup vs baseline: 13.6167x; 1.0728x over previous
//
#include <hip/hip_runtime.h>

typedef unsigned short u16;
typedef unsigned int u32;
typedef __attribute__((ext_vector_type(8))) short short8;
typedef __attribute__((ext_vector_type(4))) short short4v;
typedef __attribute__((ext_vector_type(4))) float f32x4;

__device__ __forceinline__ u16 f2bf(float f) {
    u32 u = __float_as_uint(f);
    u32 r = (u + 0x7fffu + ((u >> 16) & 1u)) >> 16;   // RNE
    return (u16)r;
}
__device__ __forceinline__ float bf2f(u16 h) {
    return __uint_as_float(((u32)h) << 16);
}

__device__ __forceinline__ void gload_lds16(const void* g, void* l) {
    __builtin_amdgcn_global_load_lds((const __attribute__((address_space(1))) void*)g,
                                     (__attribute__((address_space(3))) void*)l, 16, 0, 0);
}

#define BARRIER() do { __builtin_amdgcn_sched_barrier(0); __builtin_amdgcn_s_barrier(); __builtin_amdgcn_sched_barrier(0); } while (0)
#define VMCNT(N)  asm volatile("s_waitcnt vmcnt(" #N ")" ::: "memory")

// stage one 128-row half (2 global_load_lds per wave; dest linear, src inverse-swizzled)
#define STAGE(ptr, LDG, LOFF, RBASE, kelem) \
    do { gload_lds16((ptr) + (size_t)(RBASE) * (LDG) + (kelem),        lds + (LOFF) + ((RBASE) + (wid << 3)) * 128); \
         gload_lds16((ptr) + (size_t)((RBASE) + 64) * (LDG) + (kelem), lds + (LOFF) + ((RBASE) + 64 + (wid << 3)) * 128); } while (0)

template<int ROFF, int QH>
__device__ __forceinline__ void ld_a(short8 (&a)[4][2], const char* lds, int arow, int c0, int c1) {
    #pragma unroll
    for (int mf = 0; mf < 4; ++mf) {
        a[mf][0] = *(const short8*)(lds + ROFF + QH * 16384 + mf * 2048 + arow + c0);
        a[mf][1] = *(const short8*)(lds + ROFF + QH * 16384 + mf * 2048 + arow + c1);
    }
}
template<int ROFF, int QH>
__device__ __forceinline__ void ld_b(short8 (&b)[2][2], const char* lds, int brow, int c0, int c1) {
    #pragma unroll
    for (int nf = 0; nf < 2; ++nf) {
        b[nf][0] = *(const short8*)(lds + ROFF + QH * 16384 + nf * 2048 + brow + c0);
        b[nf][1] = *(const short8*)(lds + ROFF + QH * 16384 + nf * 2048 + brow + c1);
    }
}

template<int QM, int QN>
__device__ __forceinline__ void mfq(f32x4 (&acc)[2][4][2][2], short8 (&a)[4][2], short8 (&b)[2][2]) {
    __builtin_amdgcn_s_setprio(1);
    #pragma unroll
    for (int mf = 0; mf < 4; ++mf)
        #pragma unroll
        for (int nf = 0; nf < 2; ++nf) {
            acc[QM][mf][QN][nf] = __builtin_amdgcn_mfma_f32_16x16x32_bf16(a[mf][0], b[nf][0], acc[QM][mf][QN][nf], 0, 0, 0);
            acc[QM][mf][QN][nf] = __builtin_amdgcn_mfma_f32_16x16x32_bf16(a[mf][1], b[nf][1], acc[QM][mf][QN][nf], 0, 0, 0);
        }
    __builtin_amdgcn_s_setprio(0);
}

// ---------------------------------------------------------------------------
// 256x256 8-phase bf16 GEMM. A [M][K] rm, B [N][K] rm (transposed operand).
// Snake quadrants Q00->Q01->Q11->Q10 (B halves held in regs: 24 ds_read/tile).
// Stages: per buffer {ph+1: B0, ph+2: A0, ph+3: B1+A1}; gates vmcnt(8) at
// ph4/ph8 only -> every load has >=4-phase issue-to-gate distance.
// LDS 128 KiB: buf0A@0 buf0B@32768 buf1A@65536 buf1B@98304, [256][64] each,
// 16B-slot swizzle: LDS[row][s] = G[row][s ^ (row&7)].
// EPI: 0 = bf16 out + bias, 1 = bf16 out scaled, 2 = f32 out scaled
// ---------------------------------------------------------------------------
template<int EPI, int LDA, int LDB, int LDC, int K>
__global__ __launch_bounds__(512, 2)
void gemm8p(const u16* __restrict__ A, long long sA,
            const u16* __restrict__ B, long long sB,
            void* __restrict__ Cv, long long sC,
            const float* __restrict__ bias, float scale,
            int GX, int GY)
{
    extern __shared__ char lds[];
    const int tid  = threadIdx.x;
    const int wid  = tid >> 6;
    const int lane = tid & 63;

    // bijective XCD swizzle (all grids are multiples of 8)
    const int nwg = gridDim.x;
    int bid = blockIdx.x;
    bid = (bid & 7) * (nwg >> 3) + (bid >> 3);
    const int bx  = bid % GX;
    const int rem = bid / GX;
    const int by  = rem % GY;
    const long long z = rem / GY;

    const int bm = by * 256, bn = bx * 256;
    const u16* Atile = A + z * sA + (size_t)bm * LDA;
    const u16* Btile = B + z * sB + (size_t)bn * LDB;

    const int wm = wid >> 2, wn = wid & 3;
    const int l15   = lane & 15;
    const int lxor  = (lane & 7) << 4;
    const int khi   = (lane >> 4) << 4;
    const int colk0 = khi ^ lxor;
    const int colk1 = (64 + khi) ^ lxor;
    const int arow  = (wm * 64 + l15) * 128;
    const int brow  = (wn * 32 + l15) * 128;

    const int swz = ((lane & 7) ^ (lane >> 3)) << 3;   // inverse-swizzled src col (elems)
    const u16* pA = Atile + (size_t)((wid << 3) + (lane >> 3)) * LDA + swz;
    const u16* pB = Btile + (size_t)((wid << 3) + (lane >> 3)) * LDB + swz;

    f32x4 acc[2][4][2][2];
    #pragma unroll
    for (int i = 0; i < 2; ++i)
        #pragma unroll
        for (int m = 0; m < 4; ++m)
            #pragma unroll
            for (int j = 0; j < 2; ++j)
                #pragma unroll
                for (int n = 0; n < 2; ++n)
                    acc[i][m][j][n] = (f32x4){0.f, 0.f, 0.f, 0.f};

    // prologue: tile0 -> buf0 (8 loads), tile1 -> buf1 (8 loads)
    STAGE(pA, LDA, 0,     0,   0);  STAGE(pB, LDB, 32768, 0,   0);
    STAGE(pA, LDA, 0,     128, 0);  STAGE(pB, LDB, 32768, 128, 0);
    STAGE(pB, LDB, 98304, 0,   64); STAGE(pA, LDA, 65536, 0,   64);
    STAGE(pB, LDB, 98304, 128, 64); STAGE(pA, LDA, 65536, 128, 64);
    VMCNT(8);
    BARRIER();

    short8 a[4][2], b0[2][2], b1[2][2];
    const int NI = K >> 7;     // two 64-wide K-tiles per iteration

    for (int it = 0; it < NI; ++it) {
        const bool more = (it + 1 < NI);
        const int kn = it * 128 + 128;
        // ph1: Q(0,0) buf0
        ld_a<0, 0>(a, lds, arow, colk0, colk1);
        ld_b<32768, 0>(b0, lds, brow, colk0, colk1);
        BARRIER(); mfq<0, 0>(acc, a, b0); BARRIER();
        // ph2: Q(0,1) buf0 ; stage (T+2).B0
        ld_b<32768, 1>(b1, lds, brow, colk0, colk1);
        if (more) STAGE(pB, LDB, 32768, 0, kn);
        BARRIER(); mfq<0, 1>(acc, a, b1); BARRIER();
        // ph3: Q(1,1) buf0 ; stage (T+2).A0
        ld_a<0, 1>(a, lds, arow, colk0, colk1);
        if (more) STAGE(pA, LDA, 0, 0, kn);
        BARRIER(); mfq<1, 1>(acc, a, b1); BARRIER();
        // ph4: Q(1,0) buf0 (all regs held) ; stage (T+2).B1+A1 ; gate buf1
        if (more) { STAGE(pB, LDB, 32768, 128, kn); STAGE(pA, LDA, 0, 128, kn); VMCNT(8); }
        else      { VMCNT(0); }
        BARRIER(); mfq<1, 0>(acc, a, b0); BARRIER();
        // ph5: Q(0,0) buf1
        ld_a<65536, 0>(a, lds, arow, colk0, colk1);
        ld_b<98304, 0>(b0, lds, brow, colk0, colk1);
        BARRIER(); mfq<0, 0>(acc, a, b0); BARRIER();
        // ph6: Q(0,1) buf1 ; stage (T+3).B0
        ld_b<98304, 1>(b1, lds, brow, colk0, colk1);
        if (more) STAGE(pB, LDB, 98304, 0, kn + 64);
        BARRIER(); mfq<0, 1>(acc, a, b1); BARRIER();
        // ph7: Q(1,1) buf1 ; stage (T+3).A0
        ld_a<65536, 1>(a, lds, arow, colk0, colk1);
        if (more) STAGE(pA, LDA, 65536, 0, kn + 64);
        BARRIER(); mfq<1, 1>(acc, a, b1); BARRIER();
        // ph8: Q(1,0) buf1 ; stage (T+3).B1+A1 ; gate buf0
        if (more) { STAGE(pB, LDB, 98304, 128, kn + 64); STAGE(pA, LDA, 65536, 128, kn + 64); VMCNT(8); }
        BARRIER(); mfq<1, 0>(acc, a, b0); BARRIER();
    }

    // epilogue. C/D map (m89): col = lane&15, row = 4*(lane>>4)+reg
    const int r0 = (lane >> 4) * 4;
    const int cc = lane & 15;
    #pragma unroll
    for (int qn = 0; qn < 2; ++qn)
        #pragma unroll
        for (int nf = 0; nf < 2; ++nf) {
            const int col = bn + qn * 128 + wn * 32 + nf * 16 + cc;
            const float badd = (EPI == 0) ? bias[col] : 0.f;
            #pragma unroll
            for (int qm = 0; qm < 2; ++qm)
                #pragma unroll
                for (int mf = 0; mf < 4; ++mf) {
                    const int row = bm + qm * 128 + wm * 64 + mf * 16 + r0;
                    #pragma unroll
                    for (int r = 0; r < 4; ++r) {
                        const float v = acc[qm][mf][qn][nf][r] * scale + badd;
                        if (EPI == 2) ((float*)Cv + z * sC)[(size_t)(row + r) * LDC + col] = v;
                        else          ((u16*)Cv + z * sC)[(size_t)(row + r) * LDC + col] = f2bf(v);
                    }
                }
        }
}

// ---------------------------------------------------------------------------
__global__ __launch_bounds__(256)
void cvt_f32_bf16(const float* __restrict__ in, u16* __restrict__ out, int n8)
{
    const int i = blockIdx.x * 256 + threadIdx.x;
    if (i >= n8) return;
    const float4* p = (const float4*)in;
    const float4 a = p[2 * i], b = p[2 * i + 1];
    short8 o;
    o[0] = (short)f2bf(a.x); o[1] = (short)f2bf(a.y);
    o[2] = (short)f2bf(a.z); o[3] = (short)f2bf(a.w);
    o[4] = (short)f2bf(b.x); o[5] = (short)f2bf(b.y);
    o[6] = (short)f2bf(b.z); o[7] = (short)f2bf(b.w);
    ((short8*)out)[i] = o;
}

// W [1024][3072] f32 -> Wt [3072][1024] bf16
__global__ __launch_bounds__(256)
void cvt_w_t(const float* __restrict__ W, u16* __restrict__ Wt)
{
    __shared__ u16 T[32][33];
    const int tid = threadIdx.x;
    const int tr = tid >> 3;
    const int tc = (tid & 7) * 4;
    const int c0 = blockIdx.x * 32;
    const int r0 = blockIdx.y * 32;
    const float4 v = *(const float4*)&W[(size_t)(r0 + tr) * 3072 + c0 + tc];
    T[tr][tc + 0] = f2bf(v.x); T[tr][tc + 1] = f2bf(v.y);
    T[tr][tc + 2] = f2bf(v.z); T[tr][tc + 3] = f2bf(v.w);
    __syncthreads();
    short4v o;
    o[0] = (short)T[tc + 0][tr]; o[1] = (short)T[tc + 1][tr];
    o[2] = (short)T[tc + 2][tr]; o[3] = (short)T[tc + 3][tr];
    *(short4v*)&Wt[(size_t)(c0 + tr) * 1024 + r0 + tc] = o;
}

// qkv bf16 [B*2048][3072], V at cols 2048.. -> Vt [B][1024][2048]
__global__ __launch_bounds__(256)
void trans_v(const u16* __restrict__ qkv, u16* __restrict__ Vt)
{
    __shared__ u16 T[32][33];
    const int tid = threadIdx.x;
    const int tr = tid >> 3;
    const int tc = (tid & 7) * 4;
    const int e0 = blockIdx.x * 32;
    const int s0 = blockIdx.y * 32;
    const int b  = blockIdx.z;
    const short4v v = *(const short4v*)&qkv[(size_t)(b * 2048 + s0 + tr) * 3072 + 2048 + e0 + tc];
    T[tr][tc + 0] = (u16)v[0]; T[tr][tc + 1] = (u16)v[1];
    T[tr][tc + 2] = (u16)v[2]; T[tr][tc + 3] = (u16)v[3];
    __syncthreads();
    short4v o;
    o[0] = (short)T[tc + 0][tr]; o[1] = (short)T[tc + 1][tr];
    o[2] = (short)T[tc + 2][tr]; o[3] = (short)T[tc + 3][tr];
    *(short4v*)&Vt[(size_t)b * 1024 * 2048 + (size_t)(e0 + tr) * 2048 + s0 + tc] = o;
}

// in-place row softmax over 2048 bf16
__global__ __launch_bounds__(256)
void softmax_bf16(u16* __restrict__ S)
{
    u16* row = S + (size_t)blockIdx.x * 2048;
    const int tid  = threadIdx.x;
    const int wid  = tid >> 6;
    const int lane = tid & 63;
    __shared__ float red[4];

    const short8 v8 = *(const short8*)&row[tid * 8];
    float v[8];
    float m = -3.4e38f;
    #pragma unroll
    for (int j = 0; j < 8; ++j) { v[j] = bf2f((u16)v8[j]); m = fmaxf(m, v[j]); }
    #pragma unroll
    for (int off = 32; off; off >>= 1) m = fmaxf(m, __shfl_xor(m, off));
    if (lane == 0) red[wid] = m;
    __syncthreads();
    m = fmaxf(fmaxf(red[0], red[1]), fmaxf(red[2], red[3]));
    float s = 0.f;
    #pragma unroll
    for (int j = 0; j < 8; ++j) { v[j] = __expf(v[j] - m); s += v[j]; }
    #pragma unroll
    for (int off = 32; off; off >>= 1) s += __shfl_xor(s, off);
    __syncthreads();
    if (lane == 0) red[wid] = s;
    __syncthreads();
    s = red[0] + red[1] + red[2] + red[3];
    const float inv = 1.f / s;
    short8 o;
    #pragma unroll
    for (int j = 0; j < 8; ++j) o[j] = (short)f2bf(v[j] * inv);
    *(short8*)&row[tid * 8] = o;
}

// ---------------------------------------------------------------------------
extern "C" void kernel_launch(void* const* d_in, const int* in_sizes, int n_in,
                              void* d_out, int out_size, void* d_ws, size_t ws_size,
                              hipStream_t stream) {
    const float* x    = (const float*)d_in[0];   // [8,2048,1024]
    const float* W    = (const float*)d_in[1];   // [1024,3072]
    const float* bias = (const float*)d_in[2];   // [3072]
    float* out = (float*)d_out;                  // [8,2048,1024] f32

    const int B = 8, S = 2048, E = 1024, N3 = 3072;
    const int M = B * S;                         // 16384

    char* ws = (char*)d_ws;
    u16* xb   = (u16*)ws;                          // 32 MiB  [M][E]
    u16* Wtb  = (u16*)(ws + 33554432);             //  6 MiB  [3072][1024]
    u16* qkvb = (u16*)(ws + 39845888);             // 96 MiB  [M][3072]
    u16* Vtb  = (u16*)(ws + 140509184);            // 32 MiB  [B][1024][2048]
    u16* Sb   = (u16*)(ws + 174063616);            // 64 MiB full / 8 MiB per-batch

    const size_t need_full = 174063616ull + (size_t)B * S * S * 2;
    const bool full = ws_size >= need_full;
    const float sc = 1.0f / 32.0f;
    const int LDSB = 131072;

    // instantiations: <EPI, LDA, LDB, LDC, K>
    auto kQKV = gemm8p<0, 1024, 1024, 3072, 1024>;
    auto kQKT = gemm8p<1, 3072, 3072, 2048, 1024>;
    auto kPV  = gemm8p<2, 2048, 2048, 1024, 2048>;
    (void)hipFuncSetAttribute(reinterpret_cast<const void*>(kQKV),
                              hipFuncAttributeMaxDynamicSharedMemorySize, LDSB);
    (void)hipFuncSetAttribute(reinterpret_cast<const void*>(kQKT),
                              hipFuncAttributeMaxDynamicSharedMemorySize, LDSB);
    (void)hipFuncSetAttribute(reinterpret_cast<const void*>(kPV),
                              hipFuncAttributeMaxDynamicSharedMemorySize, LDSB);

    cvt_f32_bf16<<<dim3((M * E) / 8 / 256), 256, 0, stream>>>(x, xb, (M * E) / 8);
    cvt_w_t<<<dim3(96, 32), 256, 0, stream>>>(W, Wtb);

    // qkv = x @ W + b : grid 12 x 64
    kQKV<<<dim3(12 * 64), 512, LDSB, stream>>>(xb, 0, Wtb, 0, qkvb, 0, bias, 1.0f, 12, 64);

    trans_v<<<dim3(32, 64, 8), 256, 0, stream>>>(qkvb, Vtb);

    if (full) {
        kQKT<<<dim3(8 * 8 * 8), 512, LDSB, stream>>>(
            qkvb, (long long)S * N3, qkvb + E, (long long)S * N3,
            Sb, (long long)S * S, nullptr, sc, 8, 8);
        softmax_bf16<<<dim3(B * S), 256, 0, stream>>>(Sb);
        kPV<<<dim3(4 * 8 * 8), 512, LDSB, stream>>>(
            Sb, (long long)S * S, Vtb, (long long)E * S,
            out, (long long)S * E, nullptr, 1.0f, 4, 8);
    } else {
        for (int b = 0; b < B; ++b) {
            const u16* Qb = qkvb + (size_t)b * S * N3;
            kQKT<<<dim3(8 * 8), 512, LDSB, stream>>>(
                Qb, 0, Qb + E, 0, Sb, 0, nullptr, sc, 8, 8);
            softmax_bf16<<<dim3(S), 256, 0, stream>>>(Sb);
            kPV<<<dim3(4 * 8), 512, LDSB, stream>>>(
                Sb, 0, Vtb + (size_t)b * E * S, 0,
                out + (size_t)b * S * E, 0, nullptr, 1.0f, 4, 8);
        }
    }
}

// Round 5
// 280.535 us; speedup vs baseline: 14.2048x; 1.0432x over previous
//
#include <hip/hip_runtime.h>

typedef unsigned short u16;
typedef unsigned int u32;
typedef __attribute__((ext_vector_type(8))) short short8;
typedef __attribute__((ext_vector_type(4))) short short4v;
typedef __attribute__((ext_vector_type(4))) float f32x4;

__device__ __forceinline__ u16 f2bf(float f) {
    u32 u = __float_as_uint(f);
    u32 r = (u + 0x7fffu + ((u >> 16) & 1u)) >> 16;   // RNE
    return (u16)r;
}
__device__ __forceinline__ float bf2f(u16 h) {
    return __uint_as_float(((u32)h) << 16);
}

__device__ __forceinline__ void gload_lds16(const void* g, void* l) {
    __builtin_amdgcn_global_load_lds((const __attribute__((address_space(1))) void*)g,
                                     (__attribute__((address_space(3))) void*)l, 16, 0, 0);
}

#define BARRIER() do { __builtin_amdgcn_sched_barrier(0); __builtin_amdgcn_s_barrier(); __builtin_amdgcn_sched_barrier(0); } while (0)
#define VMCNT(N)  asm volatile("s_waitcnt vmcnt(" #N ")" ::: "memory")

// stage one 128-row half (2 global_load_lds per thread; dest linear, src inverse-swizzled)
#define STAGE(ptr, LDG, LOFF, RBASE, kelem) \
    do { gload_lds16((ptr) + (size_t)(RBASE) * (LDG) + (kelem),        lds + (LOFF) + ((RBASE) + (wid << 3)) * 128); \
         gload_lds16((ptr) + (size_t)((RBASE) + 64) * (LDG) + (kelem), lds + (LOFF) + ((RBASE) + 64 + (wid << 3)) * 128); } while (0)

template<int ROFF, int QH>
__device__ __forceinline__ void ld_a(short8 (&a)[4][2], const char* lds, int arow, int c0, int c1) {
    #pragma unroll
    for (int mf = 0; mf < 4; ++mf) {
        a[mf][0] = *(const short8*)(lds + ROFF + QH * 16384 + mf * 2048 + arow + c0);
        a[mf][1] = *(const short8*)(lds + ROFF + QH * 16384 + mf * 2048 + arow + c1);
    }
}
template<int ROFF, int QH>
__device__ __forceinline__ void ld_b(short8 (&b)[2][2], const char* lds, int brow, int c0, int c1) {
    #pragma unroll
    for (int nf = 0; nf < 2; ++nf) {
        b[nf][0] = *(const short8*)(lds + ROFF + QH * 16384 + nf * 2048 + brow + c0);
        b[nf][1] = *(const short8*)(lds + ROFF + QH * 16384 + nf * 2048 + brow + c1);
    }
}

template<int QM, int QN>
__device__ __forceinline__ void mfq(f32x4 (&acc)[2][4][2][2], short8 (&a)[4][2], short8 (&b)[2][2]) {
    __builtin_amdgcn_s_setprio(1);
    #pragma unroll
    for (int mf = 0; mf < 4; ++mf)
        #pragma unroll
        for (int nf = 0; nf < 2; ++nf) {
            acc[QM][mf][QN][nf] = __builtin_amdgcn_mfma_f32_16x16x32_bf16(a[mf][0], b[nf][0], acc[QM][mf][QN][nf], 0, 0, 0);
            acc[QM][mf][QN][nf] = __builtin_amdgcn_mfma_f32_16x16x32_bf16(a[mf][1], b[nf][1], acc[QM][mf][QN][nf], 0, 0, 0);
        }
    __builtin_amdgcn_s_setprio(0);
}

// ---------------------------------------------------------------------------
// 256x256 8-phase bf16 GEMM, ONE barrier per phase (LDS-service/MFMA overlap).
// A [M][K] rm, B [N][K] rm. Snake Q00->Q01->Q11->Q10; B halves held in regs.
// Region liveness: every stage-issue >=2 phases after region's last ds_read.
//   ph1: stage buf1.A-h1 (cur pair)   ph4: stage buf0.{A0,B0}<-T+2, gate vmcnt(4)
//   ph5: stage buf0.{A1,B1}<-T+2      ph8: stage buf1.{A0,B0,B1}<-T+3, gate vmcnt(6)
// LDS 128 KiB: buf0A@0 buf0B@32768 buf1A@65536 buf1B@98304, [256][64] each,
// 16B-slot swizzle: LDS[row][s] = G[row][s ^ (row&7)].
// EPI: 0 = bf16 out + bias, 1 = bf16 out scaled, 2 = f32 out scaled
// ---------------------------------------------------------------------------
template<int EPI, int LDA, int LDB, int LDC, int K>
__global__ __launch_bounds__(512, 2)
void gemm8p(const u16* __restrict__ A, long long sA,
            const u16* __restrict__ B, long long sB,
            void* __restrict__ Cv, long long sC,
            const float* __restrict__ bias, float scale,
            int GX, int GY)
{
    extern __shared__ char lds[];
    const int tid  = threadIdx.x;
    const int wid  = tid >> 6;
    const int lane = tid & 63;

    // bijective XCD swizzle (all grids are multiples of 8)
    const int nwg = gridDim.x;
    int bid = blockIdx.x;
    bid = (bid & 7) * (nwg >> 3) + (bid >> 3);
    const int bx  = bid % GX;
    const int rem = bid / GX;
    const int by  = rem % GY;
    const long long z = rem / GY;

    const int bm = by * 256, bn = bx * 256;
    const u16* Atile = A + z * sA + (size_t)bm * LDA;
    const u16* Btile = B + z * sB + (size_t)bn * LDB;

    const int wm = wid >> 2, wn = wid & 3;
    const int l15   = lane & 15;
    const int lxor  = (lane & 7) << 4;
    const int khi   = (lane >> 4) << 4;
    const int colk0 = khi ^ lxor;
    const int colk1 = (64 + khi) ^ lxor;
    const int arow  = (wm * 64 + l15) * 128;
    const int brow  = (wn * 32 + l15) * 128;

    const int swz = ((lane & 7) ^ (lane >> 3)) << 3;   // inverse-swizzled src col (elems)
    const u16* pA = Atile + (size_t)((wid << 3) + (lane >> 3)) * LDA + swz;
    const u16* pB = Btile + (size_t)((wid << 3) + (lane >> 3)) * LDB + swz;

    f32x4 acc[2][4][2][2];
    #pragma unroll
    for (int i = 0; i < 2; ++i)
        #pragma unroll
        for (int m = 0; m < 4; ++m)
            #pragma unroll
            for (int j = 0; j < 2; ++j)
                #pragma unroll
                for (int n = 0; n < 2; ++n)
                    acc[i][m][j][n] = (f32x4){0.f, 0.f, 0.f, 0.f};

    // prologue: buf0 <- T0 (8 loads), buf1 <- T1 halves {A0,B0,B1} (6 loads)
    STAGE(pA, LDA, 0,     0,   0);  STAGE(pB, LDB, 32768, 0,   0);
    STAGE(pA, LDA, 0,     128, 0);  STAGE(pB, LDB, 32768, 128, 0);
    STAGE(pA, LDA, 65536, 0,   64);
    STAGE(pB, LDB, 98304, 0,   64); STAGE(pB, LDB, 98304, 128, 64);
    VMCNT(6);
    BARRIER();

    short8 a[4][2], b0[2][2], b1[2][2];
    const int NI = K >> 7;     // two 64-wide K-tiles per iteration

    for (int it = 0; it < NI; ++it) {
        const bool more = (it + 1 < NI);
        const int kc0 = it * 128;          // this pair: T at kc0, T+1 at kc0+64
        const int kn  = kc0 + 128;         // next pair
        // ph1: Q00 buf0 ; stage buf1.A-h1 (completes current T+1)
        ld_a<0, 0>(a, lds, arow, colk0, colk1);
        ld_b<32768, 0>(b0, lds, brow, colk0, colk1);
        STAGE(pA, LDA, 65536, 128, kc0 + 64);
        BARRIER(); mfq<0, 0>(acc, a, b0);
        // ph2: Q01 buf0
        ld_b<32768, 1>(b1, lds, brow, colk0, colk1);
        BARRIER(); mfq<0, 1>(acc, a, b1);
        // ph3: Q11 buf0
        ld_a<0, 1>(a, lds, arow, colk0, colk1);
        BARRIER(); mfq<1, 1>(acc, a, b1);
        // ph4: Q10 buf0 (held regs) ; stage buf0.{A0,B0}<-T+2 ; gate buf1
        if (more) { STAGE(pA, LDA, 0, 0, kn); STAGE(pB, LDB, 32768, 0, kn); VMCNT(4); }
        else      { VMCNT(0); }
        BARRIER(); mfq<1, 0>(acc, a, b0);
        // ph5: Q00 buf1 ; stage buf0.{A1,B1}<-T+2
        ld_a<65536, 0>(a, lds, arow, colk0, colk1);
        ld_b<98304, 0>(b0, lds, brow, colk0, colk1);
        if (more) { STAGE(pA, LDA, 0, 128, kn); STAGE(pB, LDB, 32768, 128, kn); }
        BARRIER(); mfq<0, 0>(acc, a, b0);
        // ph6: Q01 buf1
        ld_b<98304, 1>(b1, lds, brow, colk0, colk1);
        BARRIER(); mfq<0, 1>(acc, a, b1);
        // ph7: Q11 buf1
        ld_a<65536, 1>(a, lds, arow, colk0, colk1);
        BARRIER(); mfq<1, 1>(acc, a, b1);
        // ph8: Q10 buf1 ; stage buf1.{A0,B0,B1}<-T+3 ; gate buf0
        if (more) { STAGE(pA, LDA, 65536, 0, kn + 64);
                    STAGE(pB, LDB, 98304, 0, kn + 64); STAGE(pB, LDB, 98304, 128, kn + 64);
                    VMCNT(6); }
        BARRIER(); mfq<1, 0>(acc, a, b0);
    }

    // epilogue. C/D map (m89): col = lane&15, row = 4*(lane>>4)+reg
    const int r0 = (lane >> 4) * 4;
    const int cc = lane & 15;
    #pragma unroll
    for (int qn = 0; qn < 2; ++qn)
        #pragma unroll
        for (int nf = 0; nf < 2; ++nf) {
            const int col = bn + qn * 128 + wn * 32 + nf * 16 + cc;
            const float badd = (EPI == 0) ? bias[col] : 0.f;
            #pragma unroll
            for (int qm = 0; qm < 2; ++qm)
                #pragma unroll
                for (int mf = 0; mf < 4; ++mf) {
                    const int row = bm + qm * 128 + wm * 64 + mf * 16 + r0;
                    #pragma unroll
                    for (int r = 0; r < 4; ++r) {
                        const float v = acc[qm][mf][qn][nf][r] * scale + badd;
                        if (EPI == 2) ((float*)Cv + z * sC)[(size_t)(row + r) * LDC + col] = v;
                        else          ((u16*)Cv + z * sC)[(size_t)(row + r) * LDC + col] = f2bf(v);
                    }
                }
        }
}

// ---------------------------------------------------------------------------
__global__ __launch_bounds__(256)
void cvt_f32_bf16(const float* __restrict__ in, u16* __restrict__ out, int n8)
{
    const int i = blockIdx.x * 256 + threadIdx.x;
    if (i >= n8) return;
    const float4* p = (const float4*)in;
    const float4 a = p[2 * i], b = p[2 * i + 1];
    short8 o;
    o[0] = (short)f2bf(a.x); o[1] = (short)f2bf(a.y);
    o[2] = (short)f2bf(a.z); o[3] = (short)f2bf(a.w);
    o[4] = (short)f2bf(b.x); o[5] = (short)f2bf(b.y);
    o[6] = (short)f2bf(b.z); o[7] = (short)f2bf(b.w);
    ((short8*)out)[i] = o;
}

// W [1024][3072] f32 -> Wt [3072][1024] bf16
__global__ __launch_bounds__(256)
void cvt_w_t(const float* __restrict__ W, u16* __restrict__ Wt)
{
    __shared__ u16 T[32][33];
    const int tid = threadIdx.x;
    const int tr = tid >> 3;
    const int tc = (tid & 7) * 4;
    const int c0 = blockIdx.x * 32;
    const int r0 = blockIdx.y * 32;
    const float4 v = *(const float4*)&W[(size_t)(r0 + tr) * 3072 + c0 + tc];
    T[tr][tc + 0] = f2bf(v.x); T[tr][tc + 1] = f2bf(v.y);
    T[tr][tc + 2] = f2bf(v.z); T[tr][tc + 3] = f2bf(v.w);
    __syncthreads();
    short4v o;
    o[0] = (short)T[tc + 0][tr]; o[1] = (short)T[tc + 1][tr];
    o[2] = (short)T[tc + 2][tr]; o[3] = (short)T[tc + 3][tr];
    *(short4v*)&Wt[(size_t)(c0 + tr) * 1024 + r0 + tc] = o;
}

// qkv bf16 [B*2048][3072], V at cols 2048.. -> Vt [B][1024][2048]
__global__ __launch_bounds__(256)
void trans_v(const u16* __restrict__ qkv, u16* __restrict__ Vt)
{
    __shared__ u16 T[32][33];
    const int tid = threadIdx.x;
    const int tr = tid >> 3;
    const int tc = (tid & 7) * 4;
    const int e0 = blockIdx.x * 32;
    const int s0 = blockIdx.y * 32;
    const int b  = blockIdx.z;
    const short4v v = *(const short4v*)&qkv[(size_t)(b * 2048 + s0 + tr) * 3072 + 2048 + e0 + tc];
    T[tr][tc + 0] = (u16)v[0]; T[tr][tc + 1] = (u16)v[1];
    T[tr][tc + 2] = (u16)v[2]; T[tr][tc + 3] = (u16)v[3];
    __syncthreads();
    short4v o;
    o[0] = (short)T[tc + 0][tr]; o[1] = (short)T[tc + 1][tr];
    o[2] = (short)T[tc + 2][tr]; o[3] = (short)T[tc + 3][tr];
    *(short4v*)&Vt[(size_t)b * 1024 * 2048 + (size_t)(e0 + tr) * 2048 + s0 + tc] = o;
}

// in-place row softmax over 2048 bf16
__global__ __launch_bounds__(256)
void softmax_bf16(u16* __restrict__ S)
{
    u16* row = S + (size_t)blockIdx.x * 2048;
    const int tid  = threadIdx.x;
    const int wid  = tid >> 6;
    const int lane = tid & 63;
    __shared__ float red[4];

    const short8 v8 = *(const short8*)&row[tid * 8];
    float v[8];
    float m = -3.4e38f;
    #pragma unroll
    for (int j = 0; j < 8; ++j) { v[j] = bf2f((u16)v8[j]); m = fmaxf(m, v[j]); }
    #pragma unroll
    for (int off = 32; off; off >>= 1) m = fmaxf(m, __shfl_xor(m, off));
    if (lane == 0) red[wid] = m;
    __syncthreads();
    m = fmaxf(fmaxf(red[0], red[1]), fmaxf(red[2], red[3]));
    float s = 0.f;
    #pragma unroll
    for (int j = 0; j < 8; ++j) { v[j] = __expf(v[j] - m); s += v[j]; }
    #pragma unroll
    for (int off = 32; off; off >>= 1) s += __shfl_xor(s, off);
    __syncthreads();
    if (lane == 0) red[wid] = s;
    __syncthreads();
    s = red[0] + red[1] + red[2] + red[3];
    const float inv = 1.f / s;
    short8 o;
    #pragma unroll
    for (int j = 0; j < 8; ++j) o[j] = (short)f2bf(v[j] * inv);
    *(short8*)&row[tid * 8] = o;
}

// ---------------------------------------------------------------------------
extern "C" void kernel_launch(void* const* d_in, const int* in_sizes, int n_in,
                              void* d_out, int out_size, void* d_ws, size_t ws_size,
                              hipStream_t stream) {
    const float* x    = (const float*)d_in[0];   // [8,2048,1024]
    const float* W    = (const float*)d_in[1];   // [1024,3072]
    const float* bias = (const float*)d_in[2];   // [3072]
    float* out = (float*)d_out;                  // [8,2048,1024] f32

    const int B = 8, S = 2048, E = 1024, N3 = 3072;
    const int M = B * S;                         // 16384

    char* ws = (char*)d_ws;
    u16* xb   = (u16*)ws;                          // 32 MiB  [M][E]
    u16* Wtb  = (u16*)(ws + 33554432);             //  6 MiB  [3072][1024]
    u16* qkvb = (u16*)(ws + 39845888);             // 96 MiB  [M][3072]
    u16* Vtb  = (u16*)(ws + 140509184);            // 32 MiB  [B][1024][2048]
    u16* Sb   = (u16*)(ws + 174063616);            // 64 MiB full / 8 MiB per-batch

    const size_t need_full = 174063616ull + (size_t)B * S * S * 2;
    const bool full = ws_size >= need_full;
    const float sc = 1.0f / 32.0f;
    const int LDSB = 131072;

    // instantiations: <EPI, LDA, LDB, LDC, K>
    auto kQKV = gemm8p<0, 1024, 1024, 3072, 1024>;
    auto kQKT = gemm8p<1, 3072, 3072, 2048, 1024>;
    auto kPV  = gemm8p<2, 2048, 2048, 1024, 2048>;
    (void)hipFuncSetAttribute(reinterpret_cast<const void*>(kQKV),
                              hipFuncAttributeMaxDynamicSharedMemorySize, LDSB);
    (void)hipFuncSetAttribute(reinterpret_cast<const void*>(kQKT),
                              hipFuncAttributeMaxDynamicSharedMemorySize, LDSB);
    (void)hipFuncSetAttribute(reinterpret_cast<const void*>(kPV),
                              hipFuncAttributeMaxDynamicSharedMemorySize, LDSB);

    cvt_f32_bf16<<<dim3((M * E) / 8 / 256), 256, 0, stream>>>(x, xb, (M * E) / 8);
    cvt_w_t<<<dim3(96, 32), 256, 0, stream>>>(W, Wtb);

    // qkv = x @ W + b : grid 12 x 64
    kQKV<<<dim3(12 * 64), 512, LDSB, stream>>>(xb, 0, Wtb, 0, qkvb, 0, bias, 1.0f, 12, 64);

    trans_v<<<dim3(32, 64, 8), 256, 0, stream>>>(qkvb, Vtb);

    if (full) {
        kQKT<<<dim3(8 * 8 * 8), 512, LDSB, stream>>>(
            qkvb, (long long)S * N3, qkvb + E, (long long)S * N3,
            Sb, (long long)S * S, nullptr, sc, 8, 8);
        softmax_bf16<<<dim3(B * S), 256, 0, stream>>>(Sb);
        kPV<<<dim3(4 * 8 * 8), 512, LDSB, stream>>>(
            Sb, (long long)S * S, Vtb, (long long)E * S,
            out, (long long)S * E, nullptr, 1.0f, 4, 8);
    } else {
        for (int b = 0; b < B; ++b) {
            const u16* Qb = qkvb + (size_t)b * S * N3;
            kQKT<<<dim3(8 * 8), 512, LDSB, stream>>>(
                Qb, 0, Qb + E, 0, Sb, 0, nullptr, sc, 8, 8);
            softmax_bf16<<<dim3(S), 256, 0, stream>>>(Sb);
            kPV<<<dim3(4 * 8), 512, LDSB, stream>>>(
                Sb, 0, Vtb + (size_t)b * E * S, 0,
                out + (size_t)b * S * E, 0, nullptr, 1.0f, 4, 8);
        }
    }
}